// Round 5
// baseline (13.652 us; speedup 1.0000x reference)
//
#include <hip/hip_runtime.h>

// Pesudo_RenderNet — per-camera frustum raycast into a semantic voxel grid.
// Outputs (concat float32): sem_view (1,5,64,176), depth_map (1,5,64,176).
//
// Single kernel: 4 depth-parallel lanes per pixel, direct 10-float gather +
// inline argmax per probe, shfl min-reduce, convex-interval early exit.
//
// Numerics replicate numpy fp32 exactly (validated rounds 2-4, absmax 0.0):
//  - np.linalg.inv == LAPACK sgesv (getf2 partial pivot + getrs, reciprocal
//    diag multiplies)
//  - np.einsum (optimize=False) == sequential mul+add fp32, no FMA

#define IMG_H 64
#define IMG_W 176
#define NCAM  5
#define NDEPTH 88
#define XDIM 200
#define YDIM 200
#define ZDIM 16
#define NCLS 10
#define IGN  9
#define PPC  (IMG_H * IMG_W)
#define SENT 0x7FFFFFFF
#define LANES 4

__device__ __forceinline__ float dot3(const float r[3], float v0, float v1, float v2) {
    return __fadd_rn(__fadd_rn(__fmul_rn(r[0], v0), __fmul_rn(r[1], v1)),
                     __fmul_rn(r[2], v2));
}

// 3x3 inverse replicating LAPACK sgesv in fp32 (numpy np.linalg.inv path).
__device__ void inv3x3_gesv(const float* __restrict__ m, float out[3][3]) {
    float a[3][3];
    #pragma unroll
    for (int r = 0; r < 3; ++r)
        #pragma unroll
        for (int c = 0; c < 3; ++c)
            a[r][c] = m[r * 3 + c];

    int piv0, piv1;
    {   // getf2 col 0
        int p = 0; float mx = fabsf(a[0][0]);
        if (fabsf(a[1][0]) > mx) { mx = fabsf(a[1][0]); p = 1; }
        if (fabsf(a[2][0]) > mx) { p = 2; }
        piv0 = p;
        if (p != 0) {
            #pragma unroll
            for (int c = 0; c < 3; ++c) { float t = a[0][c]; a[0][c] = a[p][c]; a[p][c] = t; }
        }
        float r0 = __fdiv_rn(1.0f, a[0][0]);
        a[1][0] = __fmul_rn(a[1][0], r0);
        a[2][0] = __fmul_rn(a[2][0], r0);
        #pragma unroll
        for (int j = 1; j < 3; ++j) {
            float t = -a[0][j];
            a[1][j] = __fadd_rn(a[1][j], __fmul_rn(a[1][0], t));
            a[2][j] = __fadd_rn(a[2][j], __fmul_rn(a[2][0], t));
        }
    }
    {   // getf2 col 1
        int p = 1; float mx = fabsf(a[1][1]);
        if (fabsf(a[2][1]) > mx) { p = 2; }
        piv1 = p;
        if (p != 1) {
            #pragma unroll
            for (int c = 0; c < 3; ++c) { float t = a[1][c]; a[1][c] = a[2][c]; a[2][c] = t; }
        }
        float r1 = __fdiv_rn(1.0f, a[1][1]);
        a[2][1] = __fmul_rn(a[2][1], r1);
        a[2][2] = __fadd_rn(a[2][2], __fmul_rn(a[2][1], -a[1][2]));
    }

    float iu0 = __fdiv_rn(1.0f, a[0][0]);
    float iu1 = __fdiv_rn(1.0f, a[1][1]);
    float iu2 = __fdiv_rn(1.0f, a[2][2]);

    #pragma unroll
    for (int k = 0; k < 3; ++k) {
        float b[3] = {0.0f, 0.0f, 0.0f};
        b[k] = 1.0f;
        { float t = b[0]; b[0] = b[piv0]; b[piv0] = t; }
        { float t = b[1]; b[1] = b[piv1]; b[piv1] = t; }
        b[1] = __fsub_rn(b[1], __fmul_rn(b[0], a[1][0]));
        b[2] = __fsub_rn(b[2], __fmul_rn(b[0], a[2][0]));
        b[2] = __fsub_rn(b[2], __fmul_rn(b[1], a[2][1]));
        b[2] = __fmul_rn(b[2], iu2);
        b[1] = __fsub_rn(b[1], __fmul_rn(b[2], a[1][2]));
        b[0] = __fsub_rn(b[0], __fmul_rn(b[2], a[0][2]));
        b[1] = __fmul_rn(b[1], iu1);
        b[0] = __fsub_rn(b[0], __fmul_rn(b[1], a[0][1]));
        b[0] = __fmul_rn(b[0], iu0);
        out[0][k] = b[0];
        out[1][k] = b[1];
        out[2][k] = b[2];
    }
}

__global__ __launch_bounds__(256)
void raycast_kernel(const float* __restrict__ c2e_rot,
                    const float* __restrict__ c2e_trans,
                    const float* __restrict__ cam2img,
                    const float* __restrict__ post_rots,
                    const float* __restrict__ post_trans,
                    const float* __restrict__ sem_map,
                    float* __restrict__ out) {
    int tid = blockIdx.x * 256 + threadIdx.x;
    int g = tid >> 2;                 // pixel id (grid sized exactly)
    int l = tid & (LANES - 1);        // depth sub-lane 0..3
    int n   = g / PPC;
    int rem = g - n * PPC;
    int h   = rem / IMG_W;
    int w   = rem - h * IMG_W;

    float iPR[3][3], iK[3][3], R[3][3];
    inv3x3_gesv(post_rots + n * 9, iPR);
    inv3x3_gesv(cam2img  + n * 9, iK);
    #pragma unroll
    for (int i = 0; i < 3; ++i)
        #pragma unroll
        for (int j = 0; j < 3; ++j)
            R[i][j] = c2e_rot[n * 9 + i * 3 + j];
    float tx  = c2e_trans[n * 3 + 0], ty  = c2e_trans[n * 3 + 1], tz  = c2e_trans[n * 3 + 2];
    float tp0 = post_trans[n * 3 + 0], tp1 = post_trans[n * 3 + 1], tp2 = post_trans[n * 3 + 2];

    float x = (float)w + 0.5f;
    float y = (float)h + 0.5f;
    float v0 = __fsub_rn(__fmul_rn(4.0f, x), tp0);
    float v1 = __fsub_rn(__fmul_rn(4.0f, y), tp1);
    float v2 = __fsub_rn(1.0f, tp2);
    float a0 = dot3(iPR[0], v0, v1, v2);
    float a1 = dot3(iPR[1], v0, v1, v2);
    float a2 = dot3(iPR[2], v0, v1, v2);

    int  code = SENT;     // (k<<8)|cls of first non-ignore in-bounds hit
    bool seen = false;    // group has observed an in-bounds depth

    #pragma unroll 1
    for (int j = 0; j < NDEPTH / LANES; ++j) {
        int k = j * LANES + l;
        float d  = __fadd_rn(1.0f, __fmul_rn(0.5f, (float)k));
        float b0 = __fmul_rn(a0, d);
        float b1 = __fmul_rn(a1, d);
        float b2 = __fmul_rn(a2, d);
        float c0 = dot3(iK[0], b0, b1, b2);
        float c1 = dot3(iK[1], b0, b1, b2);
        float c2 = dot3(iK[2], b0, b1, b2);
        float e0 = __fadd_rn(dot3(R[0], c0, c1, c2), tx);
        float e1 = __fadd_rn(dot3(R[1], c0, c1, c2), ty);
        float e2 = __fadd_rn(dot3(R[2], c0, c1, c2), tz);
        float g0 = __fsub_rn(__fmul_rn(e0, 2.5f), -100.0f);
        float g1 = __fsub_rn(__fmul_rn(e1, 2.5f), -100.0f);
        float g2 = __fsub_rn(__fmul_rn(e2, 2.5f), -3.0f);
        float n0 = __fsub_rn(__fmul_rn(__fdiv_rn(g0, 200.0f), 2.0f), 1.0f);
        float n1 = __fsub_rn(__fmul_rn(__fdiv_rn(g1, 200.0f), 2.0f), 1.0f);
        float n2 = __fsub_rn(__fmul_rn(__fdiv_rn(g2, 16.0f),  2.0f), 1.0f);
        bool inb = (n0 >= -1.0f) && (n0 <= 1.0f) &&
                   (n1 >= -1.0f) && (n1 <= 1.0f) &&
                   (n2 >= -1.0f) && (n2 <= 1.0f);
        int my = SENT;
        if (inb) {
            int ix = min(max((int)floorf(g0), 0), XDIM - 1);
            int iy = min(max((int)floorf(g1), 0), YDIM - 1);
            int iz = min(max((int)floorf(g2), 0), ZDIM - 1);
            // direct gather: 10 floats as 5 aligned float2 loads (byte offset
            // 40*v is 8B-aligned), all in flight together
            const float2* p2 = (const float2*)(sem_map + (size_t)((ix * YDIM + iy) * ZDIM + iz) * NCLS);
            float pv[NCLS];
            #pragma unroll
            for (int q = 0; q < 5; ++q) {
                float2 f = p2[q];
                pv[2 * q]     = f.x;
                pv[2 * q + 1] = f.y;
            }
            // argmax over 10 classes, first-max (softmax is monotone)
            float best = pv[0];
            int   bi   = 0;
            #pragma unroll
            for (int c = 1; c < NCLS; ++c) {
                if (pv[c] > best) { best = pv[c]; bi = c; }
            }
            if (bi != IGN) my = (k << 8) | bi;
        }
        // group-wide "any in-bounds this round"
        int ginb = inb ? 1 : 0;
        ginb |= __shfl_xor(ginb, 1, LANES);
        ginb |= __shfl_xor(ginb, 2, LANES);
        // min-reduce over the 4-lane group (k unique per lane -> first hit)
        my = min(my, __shfl_xor(my, 1, LANES));
        my = min(my, __shfl_xor(my, 2, LANES));
        if (my != SENT) { code = my; break; }
        // convexity: in-bounds depth set is a contiguous interval; once we've
        // been inside and this round saw no in-bounds depth, later depths
        // (strictly larger) cannot re-enter -> no hit possible.
        if (ginb) seen = true;
        else if (seen) break;
    }

    if (l == 0) {
        int oi = (n * IMG_H + h) * IMG_W + w;
        if (code != SENT) {
            int k = code >> 8;
            out[oi] = (float)(code & 255);
            out[NCAM * PPC + oi] = __fadd_rn(1.0f, __fmul_rn(0.5f, (float)k));
        } else {
            out[oi] = (float)IGN;
            out[NCAM * PPC + oi] = 1.0f;
        }
    }
}

extern "C" void kernel_launch(void* const* d_in, const int* in_sizes, int n_in,
                              void* d_out, int out_size, void* d_ws, size_t ws_size,
                              hipStream_t stream) {
    const float* c2e_rot    = (const float*)d_in[0];
    const float* c2e_trans  = (const float*)d_in[1];
    const float* cam2img    = (const float*)d_in[2];
    const float* post_rots  = (const float*)d_in[3];
    const float* post_trans = (const float*)d_in[4];
    // d_in[5]=bda, d_in[7]=sem_view_map, d_in[8]=occ_score : unused
    const float* sem_map    = (const float*)d_in[6];
    float* out = (float*)d_out;

    // 56320 px * 4 lanes / 256 = 880 blocks exactly
    const int total_threads = NCAM * PPC * LANES;
    raycast_kernel<<<total_threads / 256, 256, 0, stream>>>(
        c2e_rot, c2e_trans, cam2img, post_rots, post_trans, sem_map, out);
}

// Round 6
// 11.569 us; speedup vs baseline: 1.1801x; 1.1801x over previous
//
#include <hip/hip_runtime.h>

// Pesudo_RenderNet — per-camera frustum raycast into a semantic voxel grid.
// Outputs (concat float32): sem_view (1,5,64,176), depth_map (1,5,64,176).
//
// Single kernel: 8 depth-parallel lanes per pixel, direct 10-float gather +
// inline argmax per probe, shfl min-reduce, convex-interval early exit.
// Per-camera matrices (two sgesv inverses + R + translations) are computed
// ONCE PER BLOCK (each block serves exactly one camera) and shared via LDS —
// identical float values, ~2x fewer issued instructions per thread.
//
// Numerics replicate numpy fp32 exactly (validated rounds 2-5, absmax 0.0):
//  - np.linalg.inv == LAPACK sgesv (getf2 partial pivot + getrs, reciprocal
//    diag multiplies)
//  - np.einsum (optimize=False) == sequential mul+add fp32, no FMA

#define IMG_H 64
#define IMG_W 176
#define NCAM  5
#define NDEPTH 88
#define XDIM 200
#define YDIM 200
#define ZDIM 16
#define NCLS 10
#define IGN  9
#define PPC  (IMG_H * IMG_W)
#define SENT 0x7FFFFFFF
#define LANES 8
#define PIX_PER_BLK (256 / LANES)     // 32 pixels per block; 11264 % 32 == 0

__device__ __forceinline__ float dot3(const float r[3], float v0, float v1, float v2) {
    return __fadd_rn(__fadd_rn(__fmul_rn(r[0], v0), __fmul_rn(r[1], v1)),
                     __fmul_rn(r[2], v2));
}

// 3x3 inverse replicating LAPACK sgesv in fp32 (numpy np.linalg.inv path).
// Writes row-major out9[i*3+k].
__device__ void inv3x3_gesv(const float* __restrict__ m, float* __restrict__ out9) {
    float a[3][3];
    #pragma unroll
    for (int r = 0; r < 3; ++r)
        #pragma unroll
        for (int c = 0; c < 3; ++c)
            a[r][c] = m[r * 3 + c];

    int piv0, piv1;
    {   // getf2 col 0
        int p = 0; float mx = fabsf(a[0][0]);
        if (fabsf(a[1][0]) > mx) { mx = fabsf(a[1][0]); p = 1; }
        if (fabsf(a[2][0]) > mx) { p = 2; }
        piv0 = p;
        if (p != 0) {
            #pragma unroll
            for (int c = 0; c < 3; ++c) { float t = a[0][c]; a[0][c] = a[p][c]; a[p][c] = t; }
        }
        float r0 = __fdiv_rn(1.0f, a[0][0]);
        a[1][0] = __fmul_rn(a[1][0], r0);
        a[2][0] = __fmul_rn(a[2][0], r0);
        #pragma unroll
        for (int j = 1; j < 3; ++j) {
            float t = -a[0][j];
            a[1][j] = __fadd_rn(a[1][j], __fmul_rn(a[1][0], t));
            a[2][j] = __fadd_rn(a[2][j], __fmul_rn(a[2][0], t));
        }
    }
    {   // getf2 col 1
        int p = 1; float mx = fabsf(a[1][1]);
        if (fabsf(a[2][1]) > mx) { p = 2; }
        piv1 = p;
        if (p != 1) {
            #pragma unroll
            for (int c = 0; c < 3; ++c) { float t = a[1][c]; a[1][c] = a[2][c]; a[2][c] = t; }
        }
        float r1 = __fdiv_rn(1.0f, a[1][1]);
        a[2][1] = __fmul_rn(a[2][1], r1);
        a[2][2] = __fadd_rn(a[2][2], __fmul_rn(a[2][1], -a[1][2]));
    }

    float iu0 = __fdiv_rn(1.0f, a[0][0]);
    float iu1 = __fdiv_rn(1.0f, a[1][1]);
    float iu2 = __fdiv_rn(1.0f, a[2][2]);

    #pragma unroll
    for (int k = 0; k < 3; ++k) {
        float b[3] = {0.0f, 0.0f, 0.0f};
        b[k] = 1.0f;
        { float t = b[0]; b[0] = b[piv0]; b[piv0] = t; }
        { float t = b[1]; b[1] = b[piv1]; b[piv1] = t; }
        b[1] = __fsub_rn(b[1], __fmul_rn(b[0], a[1][0]));
        b[2] = __fsub_rn(b[2], __fmul_rn(b[0], a[2][0]));
        b[2] = __fsub_rn(b[2], __fmul_rn(b[1], a[2][1]));
        b[2] = __fmul_rn(b[2], iu2);
        b[1] = __fsub_rn(b[1], __fmul_rn(b[2], a[1][2]));
        b[0] = __fsub_rn(b[0], __fmul_rn(b[2], a[0][2]));
        b[1] = __fmul_rn(b[1], iu1);
        b[0] = __fsub_rn(b[0], __fmul_rn(b[1], a[0][1]));
        b[0] = __fmul_rn(b[0], iu0);
        out9[0 * 3 + k] = b[0];
        out9[1 * 3 + k] = b[1];
        out9[2 * 3 + k] = b[2];
    }
}

__global__ __launch_bounds__(256)
void raycast_kernel(const float* __restrict__ c2e_rot,
                    const float* __restrict__ c2e_trans,
                    const float* __restrict__ cam2img,
                    const float* __restrict__ post_rots,
                    const float* __restrict__ post_trans,
                    const float* __restrict__ sem_map,
                    float* __restrict__ out) {
    // camera for this block (each block covers 32 consecutive pixels of one cam)
    const int n = (int)((blockIdx.x * PIX_PER_BLK) / PPC);

    __shared__ float s_iPR[9], s_iK[9], s_R[9], s_t[6];  // c2e_t[0..2], post_t[3..5]

    int lt = threadIdx.x;
    if (lt == 0) inv3x3_gesv(post_rots + n * 9, s_iPR);
    else if (lt == 1) inv3x3_gesv(cam2img + n * 9, s_iK);
    else if (lt >= 2 && lt < 11) s_R[lt - 2] = c2e_rot[n * 9 + (lt - 2)];
    else if (lt >= 11 && lt < 14) s_t[lt - 11] = c2e_trans[n * 3 + (lt - 11)];
    else if (lt >= 14 && lt < 17) s_t[3 + lt - 14] = post_trans[n * 3 + (lt - 14)];
    __syncthreads();

    float iPR[3][3], iK[3][3], R[3][3];
    #pragma unroll
    for (int i = 0; i < 3; ++i)
        #pragma unroll
        for (int j = 0; j < 3; ++j) {
            iPR[i][j] = s_iPR[i * 3 + j];
            iK[i][j]  = s_iK[i * 3 + j];
            R[i][j]   = s_R[i * 3 + j];
        }
    float tx  = s_t[0], ty  = s_t[1], tz  = s_t[2];
    float tp0 = s_t[3], tp1 = s_t[4], tp2 = s_t[5];

    int tid = blockIdx.x * 256 + threadIdx.x;
    int g = tid / LANES;              // pixel id (grid sized exactly)
    int l = tid & (LANES - 1);        // depth sub-lane
    int rem = g - n * PPC;
    int h   = rem / IMG_W;
    int w   = rem - h * IMG_W;

    float x = (float)w + 0.5f;
    float y = (float)h + 0.5f;
    float v0 = __fsub_rn(__fmul_rn(4.0f, x), tp0);
    float v1 = __fsub_rn(__fmul_rn(4.0f, y), tp1);
    float v2 = __fsub_rn(1.0f, tp2);
    float a0 = dot3(iPR[0], v0, v1, v2);
    float a1 = dot3(iPR[1], v0, v1, v2);
    float a2 = dot3(iPR[2], v0, v1, v2);

    int  code = SENT;     // (k<<8)|cls of first non-ignore in-bounds hit
    bool seen = false;    // group has observed an in-bounds depth

    #pragma unroll 1
    for (int j = 0; j < NDEPTH / LANES; ++j) {
        int k = j * LANES + l;
        float d  = __fadd_rn(1.0f, __fmul_rn(0.5f, (float)k));
        float b0 = __fmul_rn(a0, d);
        float b1 = __fmul_rn(a1, d);
        float b2 = __fmul_rn(a2, d);
        float c0 = dot3(iK[0], b0, b1, b2);
        float c1 = dot3(iK[1], b0, b1, b2);
        float c2 = dot3(iK[2], b0, b1, b2);
        float e0 = __fadd_rn(dot3(R[0], c0, c1, c2), tx);
        float e1 = __fadd_rn(dot3(R[1], c0, c1, c2), ty);
        float e2 = __fadd_rn(dot3(R[2], c0, c1, c2), tz);
        float g0 = __fsub_rn(__fmul_rn(e0, 2.5f), -100.0f);
        float g1 = __fsub_rn(__fmul_rn(e1, 2.5f), -100.0f);
        float g2 = __fsub_rn(__fmul_rn(e2, 2.5f), -3.0f);
        float n0 = __fsub_rn(__fmul_rn(__fdiv_rn(g0, 200.0f), 2.0f), 1.0f);
        float n1 = __fsub_rn(__fmul_rn(__fdiv_rn(g1, 200.0f), 2.0f), 1.0f);
        float n2 = __fsub_rn(__fmul_rn(__fdiv_rn(g2, 16.0f),  2.0f), 1.0f);
        bool inb = (n0 >= -1.0f) && (n0 <= 1.0f) &&
                   (n1 >= -1.0f) && (n1 <= 1.0f) &&
                   (n2 >= -1.0f) && (n2 <= 1.0f);
        int my = SENT;
        if (inb) {
            int ix = min(max((int)floorf(g0), 0), XDIM - 1);
            int iy = min(max((int)floorf(g1), 0), YDIM - 1);
            int iz = min(max((int)floorf(g2), 0), ZDIM - 1);
            // direct gather: 10 floats as 5 aligned float2 loads
            const float2* p2 = (const float2*)(sem_map + (size_t)((ix * YDIM + iy) * ZDIM + iz) * NCLS);
            float pv[NCLS];
            #pragma unroll
            for (int q = 0; q < 5; ++q) {
                float2 f = p2[q];
                pv[2 * q]     = f.x;
                pv[2 * q + 1] = f.y;
            }
            // argmax over 10 classes, first-max (softmax is monotone)
            float best = pv[0];
            int   bi   = 0;
            #pragma unroll
            for (int c = 1; c < NCLS; ++c) {
                if (pv[c] > best) { best = pv[c]; bi = c; }
            }
            if (bi != IGN) my = (k << 8) | bi;
        }
        // group-wide "any in-bounds this round"
        int ginb = inb ? 1 : 0;
        ginb |= __shfl_xor(ginb, 1, LANES);
        ginb |= __shfl_xor(ginb, 2, LANES);
        ginb |= __shfl_xor(ginb, 4, LANES);
        // min-reduce over the 8-lane group (k unique per lane -> first hit)
        my = min(my, __shfl_xor(my, 1, LANES));
        my = min(my, __shfl_xor(my, 2, LANES));
        my = min(my, __shfl_xor(my, 4, LANES));
        if (my != SENT) { code = my; break; }
        // convexity: the in-bounds depth set is one contiguous interval; once
        // inside then a round with zero in-bounds lanes -> no later hit.
        if (ginb) seen = true;
        else if (seen) break;
    }

    if (l == 0) {
        int oi = (n * IMG_H + h) * IMG_W + w;
        if (code != SENT) {
            int k = code >> 8;
            out[oi] = (float)(code & 255);
            out[NCAM * PPC + oi] = __fadd_rn(1.0f, __fmul_rn(0.5f, (float)k));
        } else {
            out[oi] = (float)IGN;
            out[NCAM * PPC + oi] = 1.0f;
        }
    }
}

extern "C" void kernel_launch(void* const* d_in, const int* in_sizes, int n_in,
                              void* d_out, int out_size, void* d_ws, size_t ws_size,
                              hipStream_t stream) {
    const float* c2e_rot    = (const float*)d_in[0];
    const float* c2e_trans  = (const float*)d_in[1];
    const float* cam2img    = (const float*)d_in[2];
    const float* post_rots  = (const float*)d_in[3];
    const float* post_trans = (const float*)d_in[4];
    // d_in[5]=bda, d_in[7]=sem_view_map, d_in[8]=occ_score : unused
    const float* sem_map    = (const float*)d_in[6];
    float* out = (float*)d_out;

    // 56320 px * 8 lanes / 256 = 1760 blocks exactly
    const int total_threads = NCAM * PPC * LANES;
    raycast_kernel<<<total_threads / 256, 256, 0, stream>>>(
        c2e_rot, c2e_trans, cam2img, post_rots, post_trans, sem_map, out);
}

// Round 7
// 11.504 us; speedup vs baseline: 1.1867x; 1.0056x over previous
//
#include <hip/hip_runtime.h>

// Pesudo_RenderNet — per-camera frustum raycast into a semantic voxel grid.
// Outputs (concat float32): sem_view (1,5,64,176), depth_map (1,5,64,176).
//
// Single kernel: 8 depth-parallel lanes per pixel, direct 10-float gather +
// inline argmax per probe, single fused shfl min-reduce (hit/inb/oob encoded
// in one word), convex-interval early exit. Per-camera matrices (two sgesv
// inverses + R + translations) computed once per block, shared via LDS.
//
// Numerics replicate numpy fp32 exactly (validated rounds 2-6, absmax 0.0):
//  - np.linalg.inv == LAPACK sgesv (getf2 partial pivot + getrs, reciprocal
//    diag multiplies)
//  - np.einsum (optimize=False) == sequential mul+add fp32, no FMA
//  - x/16 == x*0.0625 (power-of-2 scaling, bit-identical IEEE)

#define IMG_H 64
#define IMG_W 176
#define NCAM  5
#define NDEPTH 88
#define XDIM 200
#define YDIM 200
#define ZDIM 16
#define NCLS 10
#define IGN  9
#define PPC  (IMG_H * IMG_W)
#define SENT 0x7FFFFFFF
#define INB_SENT 0x20000000     // in-bounds but ignore-class (hit codes < this)
#define LANES 8
#define PIX_PER_BLK (256 / LANES)     // 32 pixels per block; 11264 % 32 == 0

__device__ __forceinline__ float dot3(const float r[3], float v0, float v1, float v2) {
    return __fadd_rn(__fadd_rn(__fmul_rn(r[0], v0), __fmul_rn(r[1], v1)),
                     __fmul_rn(r[2], v2));
}

// 3x3 inverse replicating LAPACK sgesv in fp32 (numpy np.linalg.inv path).
// Writes row-major out9[i*3+k].
__device__ void inv3x3_gesv(const float* __restrict__ m, float* __restrict__ out9) {
    float a[3][3];
    #pragma unroll
    for (int r = 0; r < 3; ++r)
        #pragma unroll
        for (int c = 0; c < 3; ++c)
            a[r][c] = m[r * 3 + c];

    int piv0, piv1;
    {   // getf2 col 0
        int p = 0; float mx = fabsf(a[0][0]);
        if (fabsf(a[1][0]) > mx) { mx = fabsf(a[1][0]); p = 1; }
        if (fabsf(a[2][0]) > mx) { p = 2; }
        piv0 = p;
        if (p != 0) {
            #pragma unroll
            for (int c = 0; c < 3; ++c) { float t = a[0][c]; a[0][c] = a[p][c]; a[p][c] = t; }
        }
        float r0 = __fdiv_rn(1.0f, a[0][0]);
        a[1][0] = __fmul_rn(a[1][0], r0);
        a[2][0] = __fmul_rn(a[2][0], r0);
        #pragma unroll
        for (int j = 1; j < 3; ++j) {
            float t = -a[0][j];
            a[1][j] = __fadd_rn(a[1][j], __fmul_rn(a[1][0], t));
            a[2][j] = __fadd_rn(a[2][j], __fmul_rn(a[2][0], t));
        }
    }
    {   // getf2 col 1
        int p = 1; float mx = fabsf(a[1][1]);
        if (fabsf(a[2][1]) > mx) { p = 2; }
        piv1 = p;
        if (p != 1) {
            #pragma unroll
            for (int c = 0; c < 3; ++c) { float t = a[1][c]; a[1][c] = a[2][c]; a[2][c] = t; }
        }
        float r1 = __fdiv_rn(1.0f, a[1][1]);
        a[2][1] = __fmul_rn(a[2][1], r1);
        a[2][2] = __fadd_rn(a[2][2], __fmul_rn(a[2][1], -a[1][2]));
    }

    float iu0 = __fdiv_rn(1.0f, a[0][0]);
    float iu1 = __fdiv_rn(1.0f, a[1][1]);
    float iu2 = __fdiv_rn(1.0f, a[2][2]);

    #pragma unroll
    for (int k = 0; k < 3; ++k) {
        float b[3] = {0.0f, 0.0f, 0.0f};
        b[k] = 1.0f;
        { float t = b[0]; b[0] = b[piv0]; b[piv0] = t; }
        { float t = b[1]; b[1] = b[piv1]; b[piv1] = t; }
        b[1] = __fsub_rn(b[1], __fmul_rn(b[0], a[1][0]));
        b[2] = __fsub_rn(b[2], __fmul_rn(b[0], a[2][0]));
        b[2] = __fsub_rn(b[2], __fmul_rn(b[1], a[2][1]));
        b[2] = __fmul_rn(b[2], iu2);
        b[1] = __fsub_rn(b[1], __fmul_rn(b[2], a[1][2]));
        b[0] = __fsub_rn(b[0], __fmul_rn(b[2], a[0][2]));
        b[1] = __fmul_rn(b[1], iu1);
        b[0] = __fsub_rn(b[0], __fmul_rn(b[1], a[0][1]));
        b[0] = __fmul_rn(b[0], iu0);
        out9[0 * 3 + k] = b[0];
        out9[1 * 3 + k] = b[1];
        out9[2 * 3 + k] = b[2];
    }
}

__global__ __launch_bounds__(256)
void raycast_kernel(const float* __restrict__ c2e_rot,
                    const float* __restrict__ c2e_trans,
                    const float* __restrict__ cam2img,
                    const float* __restrict__ post_rots,
                    const float* __restrict__ post_trans,
                    const float* __restrict__ sem_map,
                    float* __restrict__ out) {
    // camera for this block (each block covers 32 consecutive pixels of one cam)
    const int n = (int)((blockIdx.x * PIX_PER_BLK) / PPC);

    __shared__ float s_iPR[9], s_iK[9], s_R[9], s_t[6];  // c2e_t[0..2], post_t[3..5]

    int lt = threadIdx.x;
    if (lt == 0) inv3x3_gesv(post_rots + n * 9, s_iPR);
    else if (lt == 1) inv3x3_gesv(cam2img + n * 9, s_iK);
    else if (lt >= 2 && lt < 11) s_R[lt - 2] = c2e_rot[n * 9 + (lt - 2)];
    else if (lt >= 11 && lt < 14) s_t[lt - 11] = c2e_trans[n * 3 + (lt - 11)];
    else if (lt >= 14 && lt < 17) s_t[3 + lt - 14] = post_trans[n * 3 + (lt - 14)];
    __syncthreads();

    float iPR[3][3], iK[3][3], R[3][3];
    #pragma unroll
    for (int i = 0; i < 3; ++i)
        #pragma unroll
        for (int j = 0; j < 3; ++j) {
            iPR[i][j] = s_iPR[i * 3 + j];
            iK[i][j]  = s_iK[i * 3 + j];
            R[i][j]   = s_R[i * 3 + j];
        }
    float tx  = s_t[0], ty  = s_t[1], tz  = s_t[2];
    float tp0 = s_t[3], tp1 = s_t[4], tp2 = s_t[5];

    int tid = blockIdx.x * 256 + threadIdx.x;
    int g = tid >> 3;                 // pixel id (grid sized exactly)
    int l = tid & (LANES - 1);        // depth sub-lane
    int rem = g - n * PPC;
    int h   = rem / IMG_W;
    int w   = rem - h * IMG_W;

    float x = (float)w + 0.5f;
    float y = (float)h + 0.5f;
    float v0 = __fsub_rn(__fmul_rn(4.0f, x), tp0);
    float v1 = __fsub_rn(__fmul_rn(4.0f, y), tp1);
    float v2 = __fsub_rn(1.0f, tp2);
    float a0 = dot3(iPR[0], v0, v1, v2);
    float a1 = dot3(iPR[1], v0, v1, v2);
    float a2 = dot3(iPR[2], v0, v1, v2);

    int  code = SENT;     // (k<<8)|cls of first non-ignore in-bounds hit
    bool seen = false;    // group has observed an in-bounds depth

    #pragma unroll 1
    for (int j = 0; j < NDEPTH / LANES; ++j) {
        int k = j * LANES + l;
        float d  = __fadd_rn(1.0f, __fmul_rn(0.5f, (float)k));
        float b0 = __fmul_rn(a0, d);
        float b1 = __fmul_rn(a1, d);
        float b2 = __fmul_rn(a2, d);
        float c0 = dot3(iK[0], b0, b1, b2);
        float c1 = dot3(iK[1], b0, b1, b2);
        float c2 = dot3(iK[2], b0, b1, b2);
        float e0 = __fadd_rn(dot3(R[0], c0, c1, c2), tx);
        float e1 = __fadd_rn(dot3(R[1], c0, c1, c2), ty);
        float e2 = __fadd_rn(dot3(R[2], c0, c1, c2), tz);
        float g0 = __fsub_rn(__fmul_rn(e0, 2.5f), -100.0f);
        float g1 = __fsub_rn(__fmul_rn(e1, 2.5f), -100.0f);
        float g2 = __fsub_rn(__fmul_rn(e2, 2.5f), -3.0f);
        float n0 = __fsub_rn(__fmul_rn(__fdiv_rn(g0, 200.0f), 2.0f), 1.0f);
        float n1 = __fsub_rn(__fmul_rn(__fdiv_rn(g1, 200.0f), 2.0f), 1.0f);
        float n2 = __fsub_rn(__fmul_rn(__fmul_rn(g2, 0.0625f), 2.0f), 1.0f); // /16 == *2^-4, bit-exact
        bool inb = (n0 >= -1.0f) && (n0 <= 1.0f) &&
                   (n1 >= -1.0f) && (n1 <= 1.0f) &&
                   (n2 >= -1.0f) && (n2 <= 1.0f);
        // single-word encode: hit code < INB_SENT < SENT
        int my = SENT;
        if (inb) {
            int ix = min(max((int)floorf(g0), 0), XDIM - 1);
            int iy = min(max((int)floorf(g1), 0), YDIM - 1);
            int iz = min(max((int)floorf(g2), 0), ZDIM - 1);
            // direct gather: 10 floats as 5 aligned float2 loads
            const float2* p2 = (const float2*)(sem_map + (size_t)((ix * YDIM + iy) * ZDIM + iz) * NCLS);
            float pv[NCLS];
            #pragma unroll
            for (int q = 0; q < 5; ++q) {
                float2 f = p2[q];
                pv[2 * q]     = f.x;
                pv[2 * q + 1] = f.y;
            }
            // argmax over 10 classes, first-max (softmax is monotone)
            float best = pv[0];
            int   bi   = 0;
            #pragma unroll
            for (int c = 1; c < NCLS; ++c) {
                if (pv[c] > best) { best = pv[c]; bi = c; }
            }
            my = (bi != IGN) ? ((k << 8) | bi) : INB_SENT;
        }
        // fused min-reduce over the 8-lane group: result is the first hit if
        // any (k unique per lane), else INB_SENT if any lane in-bounds, else SENT
        my = min(my, __shfl_xor(my, 1, LANES));
        my = min(my, __shfl_xor(my, 2, LANES));
        my = min(my, __shfl_xor(my, 4, LANES));
        if (my < INB_SENT) { code = my; break; }
        // convexity: the in-bounds depth set is one contiguous interval; once
        // inside then a round with zero in-bounds lanes -> no later hit.
        if (my == INB_SENT) seen = true;
        else if (seen) break;
    }

    if (l == 0) {
        int oi = (n * IMG_H + h) * IMG_W + w;
        if (code != SENT) {
            int k = code >> 8;
            out[oi] = (float)(code & 255);
            out[NCAM * PPC + oi] = __fadd_rn(1.0f, __fmul_rn(0.5f, (float)k));
        } else {
            out[oi] = (float)IGN;
            out[NCAM * PPC + oi] = 1.0f;
        }
    }
}

extern "C" void kernel_launch(void* const* d_in, const int* in_sizes, int n_in,
                              void* d_out, int out_size, void* d_ws, size_t ws_size,
                              hipStream_t stream) {
    const float* c2e_rot    = (const float*)d_in[0];
    const float* c2e_trans  = (const float*)d_in[1];
    const float* cam2img    = (const float*)d_in[2];
    const float* post_rots  = (const float*)d_in[3];
    const float* post_trans = (const float*)d_in[4];
    // d_in[5]=bda, d_in[7]=sem_view_map, d_in[8]=occ_score : unused
    const float* sem_map    = (const float*)d_in[6];
    float* out = (float*)d_out;

    // 56320 px * 8 lanes / 256 = 1760 blocks exactly
    const int total_threads = NCAM * PPC * LANES;
    raycast_kernel<<<total_threads / 256, 256, 0, stream>>>(
        c2e_rot, c2e_trans, cam2img, post_rots, post_trans, sem_map, out);
}